// Round 6
// baseline (232.044 us; speedup 1.0000x reference)
//
#include <hip/hip_runtime.h>
#include <math.h>

// MultiHeadAttention: B=2,S=2048,E=1024,H=16,DH=64,A=1024. fp32 in/out.
// Round 6: K-split=2 flash attention. R5 showed QT=128 starved the grid
// (512 blocks, occ 21%, all pipes idle -> latency-bound). No-max softmax
// partials compose by addition: each split writes bf16 partial-O + fp32
// partial-sum; merge kernel normalizes. Grid back to 1024 blocks (4/CU).
// d_ws bytes: [0,8)xb|Opart0 [8,16)qb [16,24)kb [24,32)vtb [32,40)cc
//             [40,46)Wt [46,48)Wot [48,56)Opart1 [56,56.5)Ssum  (<64 MB)

namespace {
constexpr int kBn = 2, kS = 2048, kE = 1024, kH = 16, kDH = 64, kA = 1024;
constexpr int kRows = kBn * kH * kS;   // 65536 q-rows total

typedef __attribute__((ext_vector_type(8))) short short8;
typedef __attribute__((ext_vector_type(4))) float f32x4;

// q pre-scale: (1/sqrt(DH)) * log2(e) so attention uses raw v_exp_f32.
#define QSCALE 0.18033688011112042f

__device__ inline unsigned short f2bf(float f) {
  union { float f; unsigned u; } x; x.f = f;
  unsigned r = x.u + 0x7fffu + ((x.u >> 16) & 1u);   // RNE
  return (unsigned short)(r >> 16);
}

__device__ inline float bf2f(unsigned short s) {
  union { unsigned u; float f; } x; x.u = ((unsigned)s) << 16;
  return x.f;
}

__device__ inline void gld16(const void* g, void* l) {
  __builtin_amdgcn_global_load_lds(
      (const __attribute__((address_space(1))) unsigned int*)g,
      (__attribute__((address_space(3))) unsigned int*)l, 16, 0, 0);
}

// ---------------- cast x: fp32 -> bf16, elementwise ----------------------
__global__ __launch_bounds__(256) void cast_x_kernel(
    const float* __restrict__ x, unsigned short* __restrict__ xb) {
  const int i = (blockIdx.x * 256 + threadIdx.x) * 8;
  float4 a = *(const float4*)(x + i);
  float4 b = *(const float4*)(x + i + 4);
  unsigned short t[8];
  t[0] = f2bf(a.x); t[1] = f2bf(a.y); t[2] = f2bf(a.z); t[3] = f2bf(a.w);
  t[4] = f2bf(b.x); t[5] = f2bf(b.y); t[6] = f2bf(b.z); t[7] = f2bf(b.w);
  *(short8*)(xb + i) = *(const short8*)t;
}

// ---------------- cast+transpose Wq/Wk/Wv: [H,E,DH] -> [sel][h*64+d][e] --
__global__ __launch_bounds__(256) void cast_wqkv_kernel(
    const float* __restrict__ Wq, const float* __restrict__ Wk,
    const float* __restrict__ Wv, unsigned short* __restrict__ Wt) {
  const int sel = blockIdx.z;
  const float* __restrict__ W = (sel == 0) ? Wq : (sel == 1) ? Wk : Wv;
  const int h = blockIdx.y;
  const int e0 = blockIdx.x * 64;
  const int tid = threadIdx.x;

  __shared__ float T[64][68];
  const int el = tid >> 2, dq = tid & 3;
  const float* src = W + ((size_t)h * kE + e0 + el) * kDH + dq * 16;
#pragma unroll
  for (int j = 0; j < 4; ++j)
    *(float4*)&T[el][dq * 16 + j * 4] = *(const float4*)(src + j * 4);
  __syncthreads();

  const int d = tid & 63, w = tid >> 6;
  unsigned short t[16];
#pragma unroll
  for (int j = 0; j < 16; ++j) t[j] = f2bf(T[w * 16 + j][d]);
  unsigned short* dst =
      Wt + (((size_t)sel << 20) | ((size_t)(h * 64 + d) << 10)) + e0 + w * 16;
  *(short8*)dst = *(const short8*)&t[0];
  *(short8*)(dst + 8) = *(const short8*)&t[8];
}

// ---------------- cast+transpose Wo: [A,E] -> [e][a] ---------------------
__global__ __launch_bounds__(256) void cast_wo_kernel(
    const float* __restrict__ Wo, unsigned short* __restrict__ Wot) {
  const int a0 = blockIdx.x * 64, e0 = blockIdx.y * 64;
  const int tid = threadIdx.x;

  __shared__ float T[64][68];
  const int al = tid >> 2, dq = tid & 3;
  const float* src = Wo + (size_t)(a0 + al) * kE + e0 + dq * 16;
#pragma unroll
  for (int j = 0; j < 4; ++j)
    *(float4*)&T[al][dq * 16 + j * 4] = *(const float4*)(src + j * 4);
  __syncthreads();

  const int e = tid & 63, w = tid >> 6;
  unsigned short t[16];
#pragma unroll
  for (int j = 0; j < 16; ++j) t[j] = f2bf(T[w * 16 + j][e]);
  unsigned short* dst = Wot + ((size_t)(e0 + e) << 10) + a0 + w * 16;
  *(short8*)dst = *(const short8*)&t[0];
  *(short8*)(dst + 8) = *(const short8*)&t[8];
}

// ---------------- bf16 MFMA GEMM, m97 structure --------------------------
// mode 0: q -> [B,H,S,DH] bf16, scaled by QSCALE. mode 1: k -> same, no scale.
// mode 2: v -> [B,H,DH,S] bf16. mode 3: out fp32 [M,1024] (+bias).
__global__ __launch_bounds__(256) void gemm_bf16_kernel(
    const unsigned short* __restrict__ A, const unsigned short* __restrict__ Bt,
    const float* __restrict__ b0, const float* __restrict__ b1,
    const float* __restrict__ b2,
    unsigned short* __restrict__ oq, unsigned short* __restrict__ okk,
    unsigned short* __restrict__ ov, float* __restrict__ of, int modeBase) {
  constexpr int K = 1024;
  const int mode = modeBase ? 3 : (int)blockIdx.z;
  const unsigned short* Bm = Bt + ((size_t)(modeBase ? 0 : blockIdx.z) << 20);
  const float* bias = (mode == 1) ? b1 : (mode == 2) ? b2 : b0;

  const int mt = blockIdx.x, nt = blockIdx.y;
  const int tid = threadIdx.x;
  const int wv = tid >> 6, lane = tid & 63, lq = lane & 15, quad = lane >> 4;
  const int wm = wv >> 1, wn = wv & 1;

  __shared__ unsigned short lA[128 * 32];
  __shared__ unsigned short lB[128 * 32];

  const int c0 = wv * 64 + lane;
  const int c1 = c0 + 256;
  const unsigned short* gA0 = A + (size_t)(mt * 128 + (c0 >> 2)) * K + (c0 & 3) * 8;
  const unsigned short* gA1 = A + (size_t)(mt * 128 + (c1 >> 2)) * K + (c1 & 3) * 8;
  const unsigned short* gB0 = Bm + (size_t)(nt * 128 + (c0 >> 2)) * K + (c0 & 3) * 8;
  const unsigned short* gB1 = Bm + (size_t)(nt * 128 + (c1 >> 2)) * K + (c1 & 3) * 8;
  unsigned short* lA0 = lA + (size_t)(wv * 64) * 8;
  unsigned short* lA1 = lA0 + 256 * 8;
  unsigned short* lB0 = lB + (size_t)(wv * 64) * 8;
  unsigned short* lB1 = lB0 + 256 * 8;

  f32x4 acc[4][4];
#pragma unroll
  for (int i = 0; i < 4; ++i)
#pragma unroll
    for (int j = 0; j < 4; ++j) acc[i][j] = (f32x4){0.f, 0.f, 0.f, 0.f};

  for (int k0 = 0; k0 < K; k0 += 32) {
    gld16(gA0 + k0, lA0);
    gld16(gA1 + k0, lA1);
    gld16(gB0 + k0, lB0);
    gld16(gB1 + k0, lB1);
    __syncthreads();
    short8 af[4], bfr[4];
#pragma unroll
    for (int i = 0; i < 4; ++i)
      af[i] = *(const short8*)&lA[(wm * 64 + i * 16 + lq) * 32 + quad * 8];
#pragma unroll
    for (int j = 0; j < 4; ++j)
      bfr[j] = *(const short8*)&lB[(wn * 64 + j * 16 + lq) * 32 + quad * 8];
#pragma unroll
    for (int i = 0; i < 4; ++i)
#pragma unroll
      for (int j = 0; j < 4; ++j)
        acc[i][j] = __builtin_amdgcn_mfma_f32_16x16x32_bf16(af[i], bfr[j],
                                                            acc[i][j], 0, 0, 0);
    __syncthreads();
  }

  const int n0 = nt * 128 + wn * 64;
  float bv4[4];
#pragma unroll
  for (int j = 0; j < 4; ++j) bv4[j] = bias[n0 + j * 16 + lq];

  if (mode == 3) {
    const int m0 = mt * 128 + wm * 64;
#pragma unroll
    for (int i = 0; i < 4; ++i)
#pragma unroll
      for (int j = 0; j < 4; ++j)
#pragma unroll
        for (int r = 0; r < 4; ++r)
          of[(size_t)(m0 + i * 16 + quad * 4 + r) * kE + n0 + j * 16 + lq] =
              acc[i][j][r] + bv4[j];
  } else {
    const int tok0 = mt * 128 + wm * 64;
    const int b = tok0 >> 11;
    const int s0 = tok0 & (kS - 1);
    const int h = n0 >> 6;
    if (mode < 2) {
      unsigned short* o = (mode == 0) ? oq : okk;
      const float scl = (mode == 0) ? QSCALE : 1.0f;
#pragma unroll
      for (int i = 0; i < 4; ++i)
#pragma unroll
        for (int j = 0; j < 4; ++j) {
          const int d = j * 16 + lq;
#pragma unroll
          for (int r = 0; r < 4; ++r) {
            const int s = s0 + i * 16 + quad * 4 + r;
            o[((size_t)(b * kH + h) * kS + s) * kDH + d] =
                f2bf((acc[i][j][r] + bv4[j]) * scl);
          }
        }
    } else {
#pragma unroll
      for (int i = 0; i < 4; ++i)
#pragma unroll
        for (int j = 0; j < 4; ++j) {
          const int d = j * 16 + lq;
          union { unsigned short u[4]; uint2 v; } pk;
#pragma unroll
          for (int r = 0; r < 4; ++r) pk.u[r] = f2bf(acc[i][j][r] + bv4[j]);
          const int s = s0 + i * 16 + quad * 4;
          *(uint2*)(ov + ((size_t)(b * kH + h) * kDH + d) * kS + s) = pk.v;
        }
    }
  }
}

// ---------------- bf16 MFMA flash attention, QT=128, K-split=2 -----------
// blockIdx.z = split; each split covers keys [split*1024, +1024).
// Writes bf16 partial-O [split-sel][bh][s][d] and fp32 partial row-sums.
#define QT 128
#define KT 64
#define LDK 72
__global__ __launch_bounds__(256) void attn_mfma_kernel(
    const unsigned short* __restrict__ q, const unsigned short* __restrict__ k,
    const unsigned short* __restrict__ vt,
    unsigned short* __restrict__ Op0, unsigned short* __restrict__ Op1,
    float* __restrict__ Ssum) {
  const int bh = blockIdx.y;
  const int split = blockIdx.z;
  const int tid = threadIdx.x;
  const int wv = tid >> 6;
  const int lane = tid & 63;
  const int lq = lane & 15;
  const int quad = lane >> 4;

  __shared__ unsigned short Ks[KT][LDK];   // [t][d]   9 KB
  __shared__ unsigned short Vt[kDH][LDK];  // [d][t]   9 KB
  __shared__ unsigned short Pb[QT][LDK];   // [q][t]  18 KB, wave-private rows

  const int q0 = blockIdx.x * QT;

  short8 qa[2][2];
#pragma unroll
  for (int mf = 0; mf < 2; ++mf) {
    const unsigned short* qbase =
        q + ((size_t)bh * kS + q0 + wv * 32 + mf * 16 + lq) * kDH;
    qa[mf][0] = *(const short8*)(qbase + quad * 8);
    qa[mf][1] = *(const short8*)(qbase + 32 + quad * 8);
  }

  f32x4 Oacc[2][4];
  f32x4 Osum[2];
#pragma unroll
  for (int mf = 0; mf < 2; ++mf) {
    Osum[mf] = (f32x4){0.f, 0.f, 0.f, 0.f};
#pragma unroll
    for (int dt = 0; dt < 4; ++dt) Oacc[mf][dt] = (f32x4){0.f, 0.f, 0.f, 0.f};
  }

  unsigned short ob[8];
#pragma unroll
  for (int i = 0; i < 8; ++i) ob[i] = 0x3F80;   // bf16 1.0
  const short8 ones = *(const short8*)ob;

  const unsigned short* kg = k + (size_t)bh * kS * kDH;
  const unsigned short* vg = vt + (size_t)bh * kDH * kS;

  const int tEnd = split * 1024 + 1024;
  for (int t0 = split * 1024; t0 < tEnd; t0 += KT) {
    __syncthreads();
#pragma unroll
    for (int p = 0; p < 2; ++p) {
      const int id = p * 256 + tid;
      const int row = id >> 3, c = (id & 7) << 3;
      *(short8*)&Ks[row][c] = *(const short8*)(kg + (size_t)(t0 + row) * kDH + c);
      *(short8*)&Vt[row][c] = *(const short8*)(vg + (size_t)row * kS + t0 + c);
    }
    __syncthreads();

    // S = Q K^T; Ks frags shared across both m-frags
    f32x4 S[2][4];
#pragma unroll
    for (int nt = 0; nt < 4; ++nt) {
      short8 kb0 = *(const short8*)&Ks[nt * 16 + lq][quad * 8];
      short8 kb1 = *(const short8*)&Ks[nt * 16 + lq][32 + quad * 8];
#pragma unroll
      for (int mf = 0; mf < 2; ++mf) {
        f32x4 acc = (f32x4){0.f, 0.f, 0.f, 0.f};
        acc = __builtin_amdgcn_mfma_f32_16x16x32_bf16(qa[mf][0], kb0, acc, 0, 0, 0);
        acc = __builtin_amdgcn_mfma_f32_16x16x32_bf16(qa[mf][1], kb1, acc, 0, 0, 0);
        S[mf][nt] = acc;
      }
    }

    // P = exp2(S) -> bf16 (half-up) -> wave-private Pb rows
#pragma unroll
    for (int mf = 0; mf < 2; ++mf)
#pragma unroll
      for (int nt = 0; nt < 4; ++nt)
#pragma unroll
        for (int r = 0; r < 4; ++r) {
          const float p = __builtin_amdgcn_exp2f(S[mf][nt][r]);
          union { float f; unsigned u; } x; x.f = p;
          Pb[wv * 32 + mf * 16 + quad * 4 + r][nt * 16 + lq] =
              (unsigned short)((x.u + 0x8000u) >> 16);
        }
    // no barrier: rows [wv*32, wv*32+32) written & read by wave wv only

    short8 pa[2][2];
#pragma unroll
    for (int mf = 0; mf < 2; ++mf) {
      pa[mf][0] = *(const short8*)&Pb[wv * 32 + mf * 16 + lq][quad * 8];
      pa[mf][1] = *(const short8*)&Pb[wv * 32 + mf * 16 + lq][32 + quad * 8];
    }

#pragma unroll
    for (int dt = 0; dt < 4; ++dt) {
      short8 vb0 = *(const short8*)&Vt[dt * 16 + lq][quad * 8];
      short8 vb1 = *(const short8*)&Vt[dt * 16 + lq][32 + quad * 8];
#pragma unroll
      for (int mf = 0; mf < 2; ++mf) {
        Oacc[mf][dt] =
            __builtin_amdgcn_mfma_f32_16x16x32_bf16(pa[mf][0], vb0, Oacc[mf][dt], 0, 0, 0);
        Oacc[mf][dt] =
            __builtin_amdgcn_mfma_f32_16x16x32_bf16(pa[mf][1], vb1, Oacc[mf][dt], 0, 0, 0);
      }
    }
#pragma unroll
    for (int mf = 0; mf < 2; ++mf) {
      Osum[mf] = __builtin_amdgcn_mfma_f32_16x16x32_bf16(pa[mf][0], ones, Osum[mf], 0, 0, 0);
      Osum[mf] = __builtin_amdgcn_mfma_f32_16x16x32_bf16(pa[mf][1], ones, Osum[mf], 0, 0, 0);
    }
  }

  // epilogue: bf16 partial O (no normalization) + fp32 partial row-sum
  unsigned short* Op = split ? Op1 : Op0;
  const size_t rbase = (size_t)bh * kS;
#pragma unroll
  for (int mf = 0; mf < 2; ++mf)
#pragma unroll
    for (int r = 0; r < 4; ++r) {
      const int qrow = q0 + wv * 32 + mf * 16 + quad * 4 + r;
      unsigned short* base = Op + (rbase + qrow) * kDH;
#pragma unroll
      for (int dt = 0; dt < 4; ++dt) base[dt * 16 + lq] = f2bf(Oacc[mf][dt][r]);
      if (lq == 0) Ssum[(size_t)split * kRows + rbase + qrow] = Osum[mf][r];
    }
}

// ---------------- merge: cc = bf16((O0+O1)/(s0+s1)) ----------------------
__global__ __launch_bounds__(256) void merge_kernel(
    const unsigned short* __restrict__ Op0, const unsigned short* __restrict__ Op1,
    const float* __restrict__ Ssum, unsigned short* __restrict__ cc) {
  const int gid = blockIdx.x * 256 + threadIdx.x;   // 0 .. 512Ki-1
  const int row = gid >> 3;                          // bh*2048 + s
  const int d0 = (gid & 7) * 8;

  const float inv = 1.0f / (Ssum[row] + Ssum[kRows + row]);

  union { short8 v; unsigned short u[8]; } a, b, o;
  a.v = *(const short8*)(Op0 + (size_t)row * kDH + d0);
  b.v = *(const short8*)(Op1 + (size_t)row * kDH + d0);
#pragma unroll
  for (int j = 0; j < 8; ++j) o.u[j] = f2bf((bf2f(a.u[j]) + bf2f(b.u[j])) * inv);

  const int bh = row >> 11, s = row & (kS - 1);
  const int bb = bh >> 4, h = bh & 15;
  *(short8*)(cc + ((size_t)(bb * kS + s) * kA) + h * kDH + d0) = o.v;
}

}  // namespace

extern "C" void kernel_launch(void* const* d_in, const int* in_sizes, int n_in,
                              void* d_out, int out_size, void* d_ws, size_t ws_size,
                              hipStream_t stream) {
  const float* x  = (const float*)d_in[0];
  const float* Wq = (const float*)d_in[1];
  const float* bq = (const float*)d_in[2];
  const float* Wk = (const float*)d_in[3];
  const float* bk = (const float*)d_in[4];
  const float* Wv = (const float*)d_in[5];
  const float* bv = (const float*)d_in[6];
  const float* Wo = (const float*)d_in[7];
  const float* bo = (const float*)d_in[8];
  float* out = (float*)d_out;

  const size_t per = (size_t)kBn * kH * kS * kDH;  // 4 Mi elems
  unsigned short* xb  = (unsigned short*)d_ws;     // dead after QKV GEMM
  unsigned short* qb  = xb + per;
  unsigned short* kb  = qb + per;
  unsigned short* vtb = kb + per;
  unsigned short* cc  = vtb + per;
  unsigned short* Wt  = cc + per;                  // 3 Mi
  unsigned short* Wot = Wt + 3 * (per / 4);
  unsigned short* Op1 = Wot + (per / 4);           // [48,56) MB
  float* Ssum = (float*)(Op1 + per);               // 2 * 64Ki fp32
  unsigned short* Op0 = xb;                        // alias: xb dead by then

  cast_x_kernel<<<dim3(per / (256 * 8)), 256, 0, stream>>>(x, xb);
  cast_wqkv_kernel<<<dim3(16, 16, 3), 256, 0, stream>>>(Wq, Wk, Wv, Wt);
  cast_wo_kernel<<<dim3(16, 16), 256, 0, stream>>>(Wo, Wot);

  gemm_bf16_kernel<<<dim3(32, 8, 3), 256, 0, stream>>>(
      xb, Wt, bq, bk, bv, qb, kb, vtb, nullptr, 0);

  attn_mfma_kernel<<<dim3(kS / QT, kBn * kH, 2), 256, 0, stream>>>(
      qb, kb, vtb, Op0, Op1, Ssum);

  merge_kernel<<<dim3(kRows * 8 / 256), 256, 0, stream>>>(Op0, Op1, Ssum, cc);

  gemm_bf16_kernel<<<dim3(32, 8, 1), 256, 0, stream>>>(
      cc, Wot, bo, nullptr, nullptr, nullptr, nullptr, nullptr, out, 1);
}

// Round 7
// 209.245 us; speedup vs baseline: 1.1090x; 1.1090x over previous
//
#include <hip/hip_runtime.h>
#include <math.h>

// MultiHeadAttention: B=2,S=2048,E=1024,H=16,DH=64,A=1024. fp32 in/out.
// Round 7: revert K-split (R6 regressed: fixed costs grew, latency unchanged).
// Attention = R4 structure (QT=64) + register prefetch of next K/V tile with
// RAW s_barrier + explicit lgkmcnt(0) (no vmcnt drain -> prefetch stays in
// flight across the barrier; __syncthreads would drain it). Out-proj gets a
// dedicated 128x64-tile GEMM (512 blocks = 2/CU instead of 1/CU).
// d_ws (bf16 elems): xb[4Mi] qb[4Mi] kb[4Mi] vtb[4Mi] cc[4Mi] Wt[3Mi] Wot[1Mi]

namespace {
constexpr int kBn = 2, kS = 2048, kE = 1024, kH = 16, kDH = 64, kA = 1024;

typedef __attribute__((ext_vector_type(8))) short short8;
typedef __attribute__((ext_vector_type(4))) float f32x4;

// q pre-scale: (1/sqrt(DH)) * log2(e) so attention uses raw v_exp_f32.
#define QSCALE 0.18033688011112042f

__device__ inline unsigned short f2bf(float f) {
  union { float f; unsigned u; } x; x.f = f;
  unsigned r = x.u + 0x7fffu + ((x.u >> 16) & 1u);   // RNE
  return (unsigned short)(r >> 16);
}

__device__ inline void gld16(const void* g, void* l) {
  __builtin_amdgcn_global_load_lds(
      (const __attribute__((address_space(1))) unsigned int*)g,
      (__attribute__((address_space(3))) unsigned int*)l, 16, 0, 0);
}

// Raw workgroup barrier: LDS ordering only (lgkmcnt), no vmcnt drain.
__device__ inline void lds_barrier() {
  asm volatile("s_waitcnt lgkmcnt(0)" ::: "memory");
  __builtin_amdgcn_s_barrier();
}

// ---------------- cast x: fp32 -> bf16, elementwise ----------------------
__global__ __launch_bounds__(256) void cast_x_kernel(
    const float* __restrict__ x, unsigned short* __restrict__ xb) {
  const int i = (blockIdx.x * 256 + threadIdx.x) * 8;
  float4 a = *(const float4*)(x + i);
  float4 b = *(const float4*)(x + i + 4);
  unsigned short t[8];
  t[0] = f2bf(a.x); t[1] = f2bf(a.y); t[2] = f2bf(a.z); t[3] = f2bf(a.w);
  t[4] = f2bf(b.x); t[5] = f2bf(b.y); t[6] = f2bf(b.z); t[7] = f2bf(b.w);
  *(short8*)(xb + i) = *(const short8*)t;
}

// ---------------- cast+transpose Wq/Wk/Wv: [H,E,DH] -> [sel][h*64+d][e] --
__global__ __launch_bounds__(256) void cast_wqkv_kernel(
    const float* __restrict__ Wq, const float* __restrict__ Wk,
    const float* __restrict__ Wv, unsigned short* __restrict__ Wt) {
  const int sel = blockIdx.z;
  const float* __restrict__ W = (sel == 0) ? Wq : (sel == 1) ? Wk : Wv;
  const int h = blockIdx.y;
  const int e0 = blockIdx.x * 64;
  const int tid = threadIdx.x;

  __shared__ float T[64][68];
  const int el = tid >> 2, dq = tid & 3;
  const float* src = W + ((size_t)h * kE + e0 + el) * kDH + dq * 16;
#pragma unroll
  for (int j = 0; j < 4; ++j)
    *(float4*)&T[el][dq * 16 + j * 4] = *(const float4*)(src + j * 4);
  __syncthreads();

  const int d = tid & 63, w = tid >> 6;
  unsigned short t[16];
#pragma unroll
  for (int j = 0; j < 16; ++j) t[j] = f2bf(T[w * 16 + j][d]);
  unsigned short* dst =
      Wt + (((size_t)sel << 20) | ((size_t)(h * 64 + d) << 10)) + e0 + w * 16;
  *(short8*)dst = *(const short8*)&t[0];
  *(short8*)(dst + 8) = *(const short8*)&t[8];
}

// ---------------- cast+transpose Wo: [A,E] -> [e][a] ---------------------
__global__ __launch_bounds__(256) void cast_wo_kernel(
    const float* __restrict__ Wo, unsigned short* __restrict__ Wot) {
  const int a0 = blockIdx.x * 64, e0 = blockIdx.y * 64;
  const int tid = threadIdx.x;

  __shared__ float T[64][68];
  const int al = tid >> 2, dq = tid & 3;
  const float* src = Wo + (size_t)(a0 + al) * kE + e0 + dq * 16;
#pragma unroll
  for (int j = 0; j < 4; ++j)
    *(float4*)&T[al][dq * 16 + j * 4] = *(const float4*)(src + j * 4);
  __syncthreads();

  const int e = tid & 63, w = tid >> 6;
  unsigned short t[16];
#pragma unroll
  for (int j = 0; j < 16; ++j) t[j] = f2bf(T[w * 16 + j][e]);
  unsigned short* dst = Wot + ((size_t)(e0 + e) << 10) + a0 + w * 16;
  *(short8*)dst = *(const short8*)&t[0];
  *(short8*)(dst + 8) = *(const short8*)&t[8];
}

// ---------------- QKV GEMM (modes 0/1/2 over blockIdx.z) -----------------
// mode 0: q -> [B,H,S,DH] bf16, scaled by QSCALE. mode 1: k -> same, no scale.
// mode 2: v -> [B,H,DH,S] bf16.
__global__ __launch_bounds__(256) void gemm_bf16_kernel(
    const unsigned short* __restrict__ A, const unsigned short* __restrict__ Bt,
    const float* __restrict__ b0, const float* __restrict__ b1,
    const float* __restrict__ b2,
    unsigned short* __restrict__ oq, unsigned short* __restrict__ okk,
    unsigned short* __restrict__ ov) {
  constexpr int K = 1024;
  const int mode = (int)blockIdx.z;
  const unsigned short* Bm = Bt + ((size_t)blockIdx.z << 20);
  const float* bias = (mode == 1) ? b1 : (mode == 2) ? b2 : b0;

  const int mt = blockIdx.x, nt = blockIdx.y;
  const int tid = threadIdx.x;
  const int wv = tid >> 6, lane = tid & 63, lq = lane & 15, quad = lane >> 4;
  const int wm = wv >> 1, wn = wv & 1;

  __shared__ unsigned short lA[128 * 32];
  __shared__ unsigned short lB[128 * 32];

  const int c0 = wv * 64 + lane;
  const int c1 = c0 + 256;
  const unsigned short* gA0 = A + (size_t)(mt * 128 + (c0 >> 2)) * K + (c0 & 3) * 8;
  const unsigned short* gA1 = A + (size_t)(mt * 128 + (c1 >> 2)) * K + (c1 & 3) * 8;
  const unsigned short* gB0 = Bm + (size_t)(nt * 128 + (c0 >> 2)) * K + (c0 & 3) * 8;
  const unsigned short* gB1 = Bm + (size_t)(nt * 128 + (c1 >> 2)) * K + (c1 & 3) * 8;
  unsigned short* lA0 = lA + (size_t)(wv * 64) * 8;
  unsigned short* lA1 = lA0 + 256 * 8;
  unsigned short* lB0 = lB + (size_t)(wv * 64) * 8;
  unsigned short* lB1 = lB0 + 256 * 8;

  f32x4 acc[4][4];
#pragma unroll
  for (int i = 0; i < 4; ++i)
#pragma unroll
    for (int j = 0; j < 4; ++j) acc[i][j] = (f32x4){0.f, 0.f, 0.f, 0.f};

  for (int k0 = 0; k0 < K; k0 += 32) {
    gld16(gA0 + k0, lA0);
    gld16(gA1 + k0, lA1);
    gld16(gB0 + k0, lB0);
    gld16(gB1 + k0, lB1);
    __syncthreads();
    short8 af[4], bfr[4];
#pragma unroll
    for (int i = 0; i < 4; ++i)
      af[i] = *(const short8*)&lA[(wm * 64 + i * 16 + lq) * 32 + quad * 8];
#pragma unroll
    for (int j = 0; j < 4; ++j)
      bfr[j] = *(const short8*)&lB[(wn * 64 + j * 16 + lq) * 32 + quad * 8];
#pragma unroll
    for (int i = 0; i < 4; ++i)
#pragma unroll
      for (int j = 0; j < 4; ++j)
        acc[i][j] = __builtin_amdgcn_mfma_f32_16x16x32_bf16(af[i], bfr[j],
                                                            acc[i][j], 0, 0, 0);
    __syncthreads();
  }

  const int n0 = nt * 128 + wn * 64;
  float bv4[4];
#pragma unroll
  for (int j = 0; j < 4; ++j) bv4[j] = bias[n0 + j * 16 + lq];

  const int tok0 = mt * 128 + wm * 64;
  const int b = tok0 >> 11;
  const int s0 = tok0 & (kS - 1);
  const int h = n0 >> 6;
  if (mode < 2) {
    unsigned short* o = (mode == 0) ? oq : okk;
    const float scl = (mode == 0) ? QSCALE : 1.0f;
#pragma unroll
    for (int i = 0; i < 4; ++i)
#pragma unroll
      for (int j = 0; j < 4; ++j) {
        const int d = j * 16 + lq;
#pragma unroll
        for (int r = 0; r < 4; ++r) {
          const int s = s0 + i * 16 + quad * 4 + r;
          o[((size_t)(b * kH + h) * kS + s) * kDH + d] =
              f2bf((acc[i][j][r] + bv4[j]) * scl);
        }
      }
  } else {
#pragma unroll
    for (int i = 0; i < 4; ++i)
#pragma unroll
      for (int j = 0; j < 4; ++j) {
        const int d = j * 16 + lq;
        union { unsigned short u[4]; uint2 v; } pk;
#pragma unroll
        for (int r = 0; r < 4; ++r) pk.u[r] = f2bf(acc[i][j][r] + bv4[j]);
        const int s = s0 + i * 16 + quad * 4;
        *(uint2*)(ov + ((size_t)(b * kH + h) * kDH + d) * kS + s) = pk.v;
      }
  }
}

// ---------------- out-proj GEMM: 128x64 tiles, fp32 out + bias -----------
// A[4096,1024] bf16 (cc), Bt[1024,1024] bf16 = Wo^T. grid (32,16) = 512 blk.
__global__ __launch_bounds__(256) void gemm_out_kernel(
    const unsigned short* __restrict__ A, const unsigned short* __restrict__ Bt,
    const float* __restrict__ bo, float* __restrict__ of) {
  constexpr int K = 1024;
  const int mt = blockIdx.x, nt = blockIdx.y;
  const int tid = threadIdx.x;
  const int wv = tid >> 6, lane = tid & 63, lq = lane & 15, quad = lane >> 4;
  const int wm = wv >> 1, wn = wv & 1;

  __shared__ unsigned short lA[128 * 32];   // 8 KB
  __shared__ unsigned short lB[64 * 32];    // 4 KB

  const int c0 = wv * 64 + lane;            // A chunk (pass 0), B chunk
  const int c1 = c0 + 256;                  // A chunk (pass 1)
  const unsigned short* gA0 = A + (size_t)(mt * 128 + (c0 >> 2)) * K + (c0 & 3) * 8;
  const unsigned short* gA1 = A + (size_t)(mt * 128 + (c1 >> 2)) * K + (c1 & 3) * 8;
  const unsigned short* gB0 = Bt + (size_t)(nt * 64 + (c0 >> 2)) * K + (c0 & 3) * 8;
  unsigned short* lA0 = lA + (size_t)(wv * 64) * 8;
  unsigned short* lA1 = lA0 + 256 * 8;
  unsigned short* lB0 = lB + (size_t)(wv * 64) * 8;

  f32x4 acc[4][2];
#pragma unroll
  for (int i = 0; i < 4; ++i)
#pragma unroll
    for (int j = 0; j < 2; ++j) acc[i][j] = (f32x4){0.f, 0.f, 0.f, 0.f};

  for (int k0 = 0; k0 < K; k0 += 32) {
    gld16(gA0 + k0, lA0);
    gld16(gA1 + k0, lA1);
    gld16(gB0 + k0, lB0);
    __syncthreads();
    short8 af[4], bfr[2];
#pragma unroll
    for (int i = 0; i < 4; ++i)
      af[i] = *(const short8*)&lA[(wm * 64 + i * 16 + lq) * 32 + quad * 8];
#pragma unroll
    for (int j = 0; j < 2; ++j)
      bfr[j] = *(const short8*)&lB[(wn * 32 + j * 16 + lq) * 32 + quad * 8];
#pragma unroll
    for (int i = 0; i < 4; ++i)
#pragma unroll
      for (int j = 0; j < 2; ++j)
        acc[i][j] = __builtin_amdgcn_mfma_f32_16x16x32_bf16(af[i], bfr[j],
                                                            acc[i][j], 0, 0, 0);
    __syncthreads();
  }

  const int n0 = nt * 64 + wn * 32;
  const int m0 = mt * 128 + wm * 64;
  float bv2[2];
#pragma unroll
  for (int j = 0; j < 2; ++j) bv2[j] = bo[n0 + j * 16 + lq];
#pragma unroll
  for (int i = 0; i < 4; ++i)
#pragma unroll
    for (int j = 0; j < 2; ++j)
#pragma unroll
      for (int r = 0; r < 4; ++r)
        of[(size_t)(m0 + i * 16 + quad * 4 + r) * kE + n0 + j * 16 + lq] =
            acc[i][j][r] + bv2[j];
}

// ---------------- bf16 MFMA flash attention, QT=64 + reg prefetch --------
// Next K/V tile prefetched into VGPRs during compute; raw barriers keep the
// prefetch loads in flight (no vmcnt drain). No-max softmax, ones-MFMA
// denominator, wave-private Pb (no barrier before PV).
#define QT 64
#define KT 64
#define LDK 72
__global__ __launch_bounds__(256) void attn_mfma_kernel(
    const unsigned short* __restrict__ q, const unsigned short* __restrict__ k,
    const unsigned short* __restrict__ vt, unsigned short* __restrict__ cc) {
  const int bh = blockIdx.y;
  const int b = bh >> 4, h = bh & 15;
  const int tid = threadIdx.x;
  const int wv = tid >> 6;
  const int lane = tid & 63;
  const int lq = lane & 15;
  const int quad = lane >> 4;

  __shared__ unsigned short Ks[KT][LDK];   // [t][d]   9 KB
  __shared__ unsigned short Vt[kDH][LDK];  // [d][t]   9 KB
  __shared__ unsigned short Pb[QT][LDK];   // [q][t]   9 KB, wave-private rows

  const int q0 = blockIdx.x * QT;

  const unsigned short* qbase = q + ((size_t)bh * kS + q0 + wv * 16 + lq) * kDH;
  const short8 qa0 = *(const short8*)(qbase + quad * 8);
  const short8 qa1 = *(const short8*)(qbase + 32 + quad * 8);

  f32x4 Oacc[4];
#pragma unroll
  for (int dt = 0; dt < 4; ++dt) Oacc[dt] = (f32x4){0.f, 0.f, 0.f, 0.f};
  f32x4 Osum = (f32x4){0.f, 0.f, 0.f, 0.f};

  unsigned short ob[8];
#pragma unroll
  for (int i = 0; i < 8; ++i) ob[i] = 0x3F80;   // bf16 1.0
  const short8 ones = *(const short8*)ob;

  const unsigned short* kg = k + (size_t)bh * kS * kDH;
  const unsigned short* vg = vt + (size_t)bh * kDH * kS;

  // staging map: thread covers chunks {tid, tid+256}: row=tid>>3 (+32), col=(tid&7)*8
  const int sr = tid >> 3;
  const int sc = (tid & 7) << 3;

  // prologue: prefetch tile 0 into registers
  short8 rk0 = *(const short8*)(kg + (size_t)sr * kDH + sc);
  short8 rk1 = *(const short8*)(kg + (size_t)(sr + 32) * kDH + sc);
  short8 rv0 = *(const short8*)(vg + (size_t)sr * kS + sc);
  short8 rv1 = *(const short8*)(vg + (size_t)(sr + 32) * kS + sc);

  for (int t0 = 0; t0 < kS; t0 += KT) {
    lds_barrier();                     // all waves done reading prev tile
    *(short8*)&Ks[sr][sc]       = rk0; // waits vmcnt for rk/rv only
    *(short8*)&Ks[sr + 32][sc]  = rk1;
    *(short8*)&Vt[sr][sc]       = rv0;
    *(short8*)&Vt[sr + 32][sc]  = rv1;
    if (t0 + KT < kS) {                // prefetch next tile (in flight
      const int tn = t0 + KT;          //  through the whole compute phase)
      rk0 = *(const short8*)(kg + (size_t)(tn + sr) * kDH + sc);
      rk1 = *(const short8*)(kg + (size_t)(tn + sr + 32) * kDH + sc);
      rv0 = *(const short8*)(vg + (size_t)sr * kS + tn + sc);
      rv1 = *(const short8*)(vg + (size_t)(sr + 32) * kS + tn + sc);
    }
    lds_barrier();                     // tile visible to all waves

    // S = Q K^T (q pre-scaled -> log2 domain)
    f32x4 S[4];
#pragma unroll
    for (int nt = 0; nt < 4; ++nt) {
      short8 b0 = *(const short8*)&Ks[nt * 16 + lq][quad * 8];
      short8 b1 = *(const short8*)&Ks[nt * 16 + lq][32 + quad * 8];
      f32x4 acc = (f32x4){0.f, 0.f, 0.f, 0.f};
      acc = __builtin_amdgcn_mfma_f32_16x16x32_bf16(qa0, b0, acc, 0, 0, 0);
      acc = __builtin_amdgcn_mfma_f32_16x16x32_bf16(qa1, b1, acc, 0, 0, 0);
      S[nt] = acc;
    }

    // P = exp2(S) -> bf16 (half-up) -> wave-private Pb rows
#pragma unroll
    for (int nt = 0; nt < 4; ++nt)
#pragma unroll
      for (int r = 0; r < 4; ++r) {
        const float p = __builtin_amdgcn_exp2f(S[nt][r]);
        union { float f; unsigned u; } x; x.f = p;
        Pb[wv * 16 + quad * 4 + r][nt * 16 + lq] =
            (unsigned short)((x.u + 0x8000u) >> 16);
      }
    // no barrier: Pb rows [wv*16, wv*16+16) written & read by wave wv only

    const short8 pa0 = *(const short8*)&Pb[wv * 16 + lq][quad * 8];
    const short8 pa1 = *(const short8*)&Pb[wv * 16 + lq][32 + quad * 8];
#pragma unroll
    for (int dt = 0; dt < 4; ++dt) {
      short8 vb0 = *(const short8*)&Vt[dt * 16 + lq][quad * 8];
      short8 vb1 = *(const short8*)&Vt[dt * 16 + lq][32 + quad * 8];
      Oacc[dt] = __builtin_amdgcn_mfma_f32_16x16x32_bf16(pa0, vb0, Oacc[dt], 0, 0, 0);
      Oacc[dt] = __builtin_amdgcn_mfma_f32_16x16x32_bf16(pa1, vb1, Oacc[dt], 0, 0, 0);
    }
    Osum = __builtin_amdgcn_mfma_f32_16x16x32_bf16(pa0, ones, Osum, 0, 0, 0);
    Osum = __builtin_amdgcn_mfma_f32_16x16x32_bf16(pa1, ones, Osum, 0, 0, 0);
  }

#pragma unroll
  for (int r = 0; r < 4; ++r) {
    const float inv = 1.0f / Osum[r];
    const int qrow = q0 + wv * 16 + quad * 4 + r;
    unsigned short* base = cc + ((size_t)b * kS + qrow) * kA + h * kDH;
#pragma unroll
    for (int dt = 0; dt < 4; ++dt) base[dt * 16 + lq] = f2bf(Oacc[dt][r] * inv);
  }
}

}  // namespace

extern "C" void kernel_launch(void* const* d_in, const int* in_sizes, int n_in,
                              void* d_out, int out_size, void* d_ws, size_t ws_size,
                              hipStream_t stream) {
  const float* x  = (const float*)d_in[0];
  const float* Wq = (const float*)d_in[1];
  const float* bq = (const float*)d_in[2];
  const float* Wk = (const float*)d_in[3];
  const float* bk = (const float*)d_in[4];
  const float* Wv = (const float*)d_in[5];
  const float* bv = (const float*)d_in[6];
  const float* Wo = (const float*)d_in[7];
  const float* bo = (const float*)d_in[8];
  float* out = (float*)d_out;

  const size_t per = (size_t)kBn * kH * kS * kDH;  // 4 Mi elems
  unsigned short* xb  = (unsigned short*)d_ws;
  unsigned short* qb  = xb + per;
  unsigned short* kb  = qb + per;
  unsigned short* vtb = kb + per;
  unsigned short* cc  = vtb + per;
  unsigned short* Wt  = cc + per;          // 3 Mi
  unsigned short* Wot = Wt + 3 * (per / 4);

  cast_x_kernel<<<dim3(per / (256 * 8)), 256, 0, stream>>>(x, xb);
  cast_wqkv_kernel<<<dim3(16, 16, 3), 256, 0, stream>>>(Wq, Wk, Wv, Wt);
  cast_wo_kernel<<<dim3(16, 16), 256, 0, stream>>>(Wo, Wot);

  gemm_bf16_kernel<<<dim3(32, 8, 3), 256, 0, stream>>>(
      xb, Wt, bq, bk, bv, qb, kb, vtb);

  attn_mfma_kernel<<<dim3(kS / QT, kBn * kH), 256, 0, stream>>>(qb, kb, vtb, cc);

  gemm_out_kernel<<<dim3(32, 16), 256, 0, stream>>>(cc, Wot, bo, out);
}

// Round 8
// 197.732 us; speedup vs baseline: 1.1735x; 1.0582x over previous
//
#include <hip/hip_runtime.h>
#include <math.h>

// MultiHeadAttention: B=2,S=2048,E=1024,H=16,DH=64,A=1024. fp32 in/out.
// Round 8: attention QT=128 (2 m-frags/wave, K/V frag reuse in registers)
// COMBINED with R7's register prefetch + raw lds_barrier. R7 counters showed
// LDS pipe ~54% busy and per-wave K/V reads irreducible without more rows
// per wave; R5 (QT=128 alone) failed only for latency reasons now fixed.
// d_ws (bf16 elems): xb[4Mi] qb[4Mi] kb[4Mi] vtb[4Mi] cc[4Mi] Wt[3Mi] Wot[1Mi]

namespace {
constexpr int kBn = 2, kS = 2048, kE = 1024, kH = 16, kDH = 64, kA = 1024;

typedef __attribute__((ext_vector_type(8))) short short8;
typedef __attribute__((ext_vector_type(4))) float f32x4;

// q pre-scale: (1/sqrt(DH)) * log2(e) so attention uses raw v_exp_f32.
#define QSCALE 0.18033688011112042f

__device__ inline unsigned short f2bf(float f) {
  union { float f; unsigned u; } x; x.f = f;
  unsigned r = x.u + 0x7fffu + ((x.u >> 16) & 1u);   // RNE
  return (unsigned short)(r >> 16);
}

__device__ inline void gld16(const void* g, void* l) {
  __builtin_amdgcn_global_load_lds(
      (const __attribute__((address_space(1))) unsigned int*)g,
      (__attribute__((address_space(3))) unsigned int*)l, 16, 0, 0);
}

// Raw workgroup barrier: LDS ordering only (lgkmcnt), no vmcnt drain.
__device__ inline void lds_barrier() {
  asm volatile("s_waitcnt lgkmcnt(0)" ::: "memory");
  __builtin_amdgcn_s_barrier();
}

// ---------------- cast x: fp32 -> bf16, elementwise ----------------------
__global__ __launch_bounds__(256) void cast_x_kernel(
    const float* __restrict__ x, unsigned short* __restrict__ xb) {
  const int i = (blockIdx.x * 256 + threadIdx.x) * 8;
  float4 a = *(const float4*)(x + i);
  float4 b = *(const float4*)(x + i + 4);
  unsigned short t[8];
  t[0] = f2bf(a.x); t[1] = f2bf(a.y); t[2] = f2bf(a.z); t[3] = f2bf(a.w);
  t[4] = f2bf(b.x); t[5] = f2bf(b.y); t[6] = f2bf(b.z); t[7] = f2bf(b.w);
  *(short8*)(xb + i) = *(const short8*)t;
}

// ---------------- cast+transpose Wq/Wk/Wv: [H,E,DH] -> [sel][h*64+d][e] --
__global__ __launch_bounds__(256) void cast_wqkv_kernel(
    const float* __restrict__ Wq, const float* __restrict__ Wk,
    const float* __restrict__ Wv, unsigned short* __restrict__ Wt) {
  const int sel = blockIdx.z;
  const float* __restrict__ W = (sel == 0) ? Wq : (sel == 1) ? Wk : Wv;
  const int h = blockIdx.y;
  const int e0 = blockIdx.x * 64;
  const int tid = threadIdx.x;

  __shared__ float T[64][68];
  const int el = tid >> 2, dq = tid & 3;
  const float* src = W + ((size_t)h * kE + e0 + el) * kDH + dq * 16;
#pragma unroll
  for (int j = 0; j < 4; ++j)
    *(float4*)&T[el][dq * 16 + j * 4] = *(const float4*)(src + j * 4);
  __syncthreads();

  const int d = tid & 63, w = tid >> 6;
  unsigned short t[16];
#pragma unroll
  for (int j = 0; j < 16; ++j) t[j] = f2bf(T[w * 16 + j][d]);
  unsigned short* dst =
      Wt + (((size_t)sel << 20) | ((size_t)(h * 64 + d) << 10)) + e0 + w * 16;
  *(short8*)dst = *(const short8*)&t[0];
  *(short8*)(dst + 8) = *(const short8*)&t[8];
}

// ---------------- cast+transpose Wo: [A,E] -> [e][a] ---------------------
__global__ __launch_bounds__(256) void cast_wo_kernel(
    const float* __restrict__ Wo, unsigned short* __restrict__ Wot) {
  const int a0 = blockIdx.x * 64, e0 = blockIdx.y * 64;
  const int tid = threadIdx.x;

  __shared__ float T[64][68];
  const int al = tid >> 2, dq = tid & 3;
  const float* src = Wo + (size_t)(a0 + al) * kE + e0 + dq * 16;
#pragma unroll
  for (int j = 0; j < 4; ++j)
    *(float4*)&T[al][dq * 16 + j * 4] = *(const float4*)(src + j * 4);
  __syncthreads();

  const int e = tid & 63, w = tid >> 6;
  unsigned short t[16];
#pragma unroll
  for (int j = 0; j < 16; ++j) t[j] = f2bf(T[w * 16 + j][e]);
  unsigned short* dst = Wot + ((size_t)(e0 + e) << 10) + a0 + w * 16;
  *(short8*)dst = *(const short8*)&t[0];
  *(short8*)(dst + 8) = *(const short8*)&t[8];
}

// ---------------- QKV GEMM (modes 0/1/2 over blockIdx.z) -----------------
// mode 0: q -> [B,H,S,DH] bf16, scaled by QSCALE. mode 1: k -> same, no scale.
// mode 2: v -> [B,H,DH,S] bf16.
__global__ __launch_bounds__(256) void gemm_bf16_kernel(
    const unsigned short* __restrict__ A, const unsigned short* __restrict__ Bt,
    const float* __restrict__ b0, const float* __restrict__ b1,
    const float* __restrict__ b2,
    unsigned short* __restrict__ oq, unsigned short* __restrict__ okk,
    unsigned short* __restrict__ ov) {
  constexpr int K = 1024;
  const int mode = (int)blockIdx.z;
  const unsigned short* Bm = Bt + ((size_t)blockIdx.z << 20);
  const float* bias = (mode == 1) ? b1 : (mode == 2) ? b2 : b0;

  const int mt = blockIdx.x, nt = blockIdx.y;
  const int tid = threadIdx.x;
  const int wv = tid >> 6, lane = tid & 63, lq = lane & 15, quad = lane >> 4;
  const int wm = wv >> 1, wn = wv & 1;

  __shared__ unsigned short lA[128 * 32];
  __shared__ unsigned short lB[128 * 32];

  const int c0 = wv * 64 + lane;
  const int c1 = c0 + 256;
  const unsigned short* gA0 = A + (size_t)(mt * 128 + (c0 >> 2)) * K + (c0 & 3) * 8;
  const unsigned short* gA1 = A + (size_t)(mt * 128 + (c1 >> 2)) * K + (c1 & 3) * 8;
  const unsigned short* gB0 = Bm + (size_t)(nt * 128 + (c0 >> 2)) * K + (c0 & 3) * 8;
  const unsigned short* gB1 = Bm + (size_t)(nt * 128 + (c1 >> 2)) * K + (c1 & 3) * 8;
  unsigned short* lA0 = lA + (size_t)(wv * 64) * 8;
  unsigned short* lA1 = lA0 + 256 * 8;
  unsigned short* lB0 = lB + (size_t)(wv * 64) * 8;
  unsigned short* lB1 = lB0 + 256 * 8;

  f32x4 acc[4][4];
#pragma unroll
  for (int i = 0; i < 4; ++i)
#pragma unroll
    for (int j = 0; j < 4; ++j) acc[i][j] = (f32x4){0.f, 0.f, 0.f, 0.f};

  for (int k0 = 0; k0 < K; k0 += 32) {
    gld16(gA0 + k0, lA0);
    gld16(gA1 + k0, lA1);
    gld16(gB0 + k0, lB0);
    gld16(gB1 + k0, lB1);
    __syncthreads();
    short8 af[4], bfr[4];
#pragma unroll
    for (int i = 0; i < 4; ++i)
      af[i] = *(const short8*)&lA[(wm * 64 + i * 16 + lq) * 32 + quad * 8];
#pragma unroll
    for (int j = 0; j < 4; ++j)
      bfr[j] = *(const short8*)&lB[(wn * 64 + j * 16 + lq) * 32 + quad * 8];
#pragma unroll
    for (int i = 0; i < 4; ++i)
#pragma unroll
      for (int j = 0; j < 4; ++j)
        acc[i][j] = __builtin_amdgcn_mfma_f32_16x16x32_bf16(af[i], bfr[j],
                                                            acc[i][j], 0, 0, 0);
    __syncthreads();
  }

  const int n0 = nt * 128 + wn * 64;
  float bv4[4];
#pragma unroll
  for (int j = 0; j < 4; ++j) bv4[j] = bias[n0 + j * 16 + lq];

  const int tok0 = mt * 128 + wm * 64;
  const int b = tok0 >> 11;
  const int s0 = tok0 & (kS - 1);
  const int h = n0 >> 6;
  if (mode < 2) {
    unsigned short* o = (mode == 0) ? oq : okk;
    const float scl = (mode == 0) ? QSCALE : 1.0f;
#pragma unroll
    for (int i = 0; i < 4; ++i)
#pragma unroll
      for (int j = 0; j < 4; ++j) {
        const int d = j * 16 + lq;
#pragma unroll
        for (int r = 0; r < 4; ++r) {
          const int s = s0 + i * 16 + quad * 4 + r;
          o[((size_t)(b * kH + h) * kS + s) * kDH + d] =
              f2bf((acc[i][j][r] + bv4[j]) * scl);
        }
      }
  } else {
#pragma unroll
    for (int i = 0; i < 4; ++i)
#pragma unroll
      for (int j = 0; j < 4; ++j) {
        const int d = j * 16 + lq;
        union { unsigned short u[4]; uint2 v; } pk;
#pragma unroll
        for (int r = 0; r < 4; ++r) pk.u[r] = f2bf(acc[i][j][r] + bv4[j]);
        const int s = s0 + i * 16 + quad * 4;
        *(uint2*)(ov + ((size_t)(b * kH + h) * kDH + d) * kS + s) = pk.v;
      }
  }
}

// ---------------- out-proj GEMM: 128x64 tiles, fp32 out + bias -----------
// A[4096,1024] bf16 (cc), Bt[1024,1024] bf16 = Wo^T. grid (32,16) = 512 blk.
__global__ __launch_bounds__(256) void gemm_out_kernel(
    const unsigned short* __restrict__ A, const unsigned short* __restrict__ Bt,
    const float* __restrict__ bo, float* __restrict__ of) {
  constexpr int K = 1024;
  const int mt = blockIdx.x, nt = blockIdx.y;
  const int tid = threadIdx.x;
  const int wv = tid >> 6, lane = tid & 63, lq = lane & 15, quad = lane >> 4;
  const int wm = wv >> 1, wn = wv & 1;

  __shared__ unsigned short lA[128 * 32];   // 8 KB
  __shared__ unsigned short lB[64 * 32];    // 4 KB

  const int c0 = wv * 64 + lane;
  const int c1 = c0 + 256;
  const unsigned short* gA0 = A + (size_t)(mt * 128 + (c0 >> 2)) * K + (c0 & 3) * 8;
  const unsigned short* gA1 = A + (size_t)(mt * 128 + (c1 >> 2)) * K + (c1 & 3) * 8;
  const unsigned short* gB0 = Bt + (size_t)(nt * 64 + (c0 >> 2)) * K + (c0 & 3) * 8;
  unsigned short* lA0 = lA + (size_t)(wv * 64) * 8;
  unsigned short* lA1 = lA0 + 256 * 8;
  unsigned short* lB0 = lB + (size_t)(wv * 64) * 8;

  f32x4 acc[4][2];
#pragma unroll
  for (int i = 0; i < 4; ++i)
#pragma unroll
    for (int j = 0; j < 2; ++j) acc[i][j] = (f32x4){0.f, 0.f, 0.f, 0.f};

  for (int k0 = 0; k0 < K; k0 += 32) {
    gld16(gA0 + k0, lA0);
    gld16(gA1 + k0, lA1);
    gld16(gB0 + k0, lB0);
    __syncthreads();
    short8 af[4], bfr[2];
#pragma unroll
    for (int i = 0; i < 4; ++i)
      af[i] = *(const short8*)&lA[(wm * 64 + i * 16 + lq) * 32 + quad * 8];
#pragma unroll
    for (int j = 0; j < 2; ++j)
      bfr[j] = *(const short8*)&lB[(wn * 32 + j * 16 + lq) * 32 + quad * 8];
#pragma unroll
    for (int i = 0; i < 4; ++i)
#pragma unroll
      for (int j = 0; j < 2; ++j)
        acc[i][j] = __builtin_amdgcn_mfma_f32_16x16x32_bf16(af[i], bfr[j],
                                                            acc[i][j], 0, 0, 0);
    __syncthreads();
  }

  const int n0 = nt * 64 + wn * 32;
  const int m0 = mt * 128 + wm * 64;
  float bv2[2];
#pragma unroll
  for (int j = 0; j < 2; ++j) bv2[j] = bo[n0 + j * 16 + lq];
#pragma unroll
  for (int i = 0; i < 4; ++i)
#pragma unroll
    for (int j = 0; j < 2; ++j)
#pragma unroll
      for (int r = 0; r < 4; ++r)
        of[(size_t)(m0 + i * 16 + quad * 4 + r) * kE + n0 + j * 16 + lq] =
            acc[i][j][r] + bv2[j];
}

// ---------------- bf16 MFMA flash attention, QT=128 + prefetch -----------
// 4 waves; wave wv owns q-rows [wv*32, +32) as 2 m-frags: each Ks/Vt frag
// read from LDS feeds both m-frags (per-row LDS traffic ~halved vs QT=64).
// Next K/V tile prefetched into VGPRs during compute; raw barriers keep the
// prefetch in flight (no vmcnt drain). No-max softmax, ones-MFMA
// denominator, wave-private Pb rows (no barrier before PV).
#define QT 128
#define KT 64
#define LDK 72
__global__ __launch_bounds__(256) void attn_mfma_kernel(
    const unsigned short* __restrict__ q, const unsigned short* __restrict__ k,
    const unsigned short* __restrict__ vt, unsigned short* __restrict__ cc) {
  const int bh = blockIdx.y;
  const int b = bh >> 4, h = bh & 15;
  const int tid = threadIdx.x;
  const int wv = tid >> 6;
  const int lane = tid & 63;
  const int lq = lane & 15;
  const int quad = lane >> 4;

  __shared__ unsigned short Ks[KT][LDK];   // [t][d]   9 KB
  __shared__ unsigned short Vt[kDH][LDK];  // [d][t]   9 KB
  __shared__ unsigned short Pb[QT][LDK];   // [q][t]  18 KB, wave-private rows

  const int q0 = blockIdx.x * QT;

  short8 qa[2][2];
#pragma unroll
  for (int mf = 0; mf < 2; ++mf) {
    const unsigned short* qbase =
        q + ((size_t)bh * kS + q0 + wv * 32 + mf * 16 + lq) * kDH;
    qa[mf][0] = *(const short8*)(qbase + quad * 8);
    qa[mf][1] = *(const short8*)(qbase + 32 + quad * 8);
  }

  f32x4 Oacc[2][4];
  f32x4 Osum[2];
#pragma unroll
  for (int mf = 0; mf < 2; ++mf) {
    Osum[mf] = (f32x4){0.f, 0.f, 0.f, 0.f};
#pragma unroll
    for (int dt = 0; dt < 4; ++dt) Oacc[mf][dt] = (f32x4){0.f, 0.f, 0.f, 0.f};
  }

  unsigned short ob[8];
#pragma unroll
  for (int i = 0; i < 8; ++i) ob[i] = 0x3F80;   // bf16 1.0
  const short8 ones = *(const short8*)ob;

  const unsigned short* kg = k + (size_t)bh * kS * kDH;
  const unsigned short* vg = vt + (size_t)bh * kDH * kS;

  // staging map: thread covers chunks {tid, tid+256}: row=tid>>3 (+32), col=(tid&7)*8
  const int sr = tid >> 3;
  const int sc = (tid & 7) << 3;

  // prologue: prefetch tile 0 into registers
  short8 rk0 = *(const short8*)(kg + (size_t)sr * kDH + sc);
  short8 rk1 = *(const short8*)(kg + (size_t)(sr + 32) * kDH + sc);
  short8 rv0 = *(const short8*)(vg + (size_t)sr * kS + sc);
  short8 rv1 = *(const short8*)(vg + (size_t)(sr + 32) * kS + sc);

  for (int t0 = 0; t0 < kS; t0 += KT) {
    lds_barrier();                     // all waves done reading prev tile
    *(short8*)&Ks[sr][sc]       = rk0; // waits vmcnt for rk/rv only
    *(short8*)&Ks[sr + 32][sc]  = rk1;
    *(short8*)&Vt[sr][sc]       = rv0;
    *(short8*)&Vt[sr + 32][sc]  = rv1;
    if (t0 + KT < kS) {                // prefetch next tile (in flight
      const int tn = t0 + KT;          //  through the whole compute phase)
      rk0 = *(const short8*)(kg + (size_t)(tn + sr) * kDH + sc);
      rk1 = *(const short8*)(kg + (size_t)(tn + sr + 32) * kDH + sc);
      rv0 = *(const short8*)(vg + (size_t)sr * kS + tn + sc);
      rv1 = *(const short8*)(vg + (size_t)(sr + 32) * kS + tn + sc);
    }
    lds_barrier();                     // tile visible to all waves

    // S = Q K^T; Ks frags read once, reused for both m-frags
    f32x4 S[2][4];
#pragma unroll
    for (int nt = 0; nt < 4; ++nt) {
      short8 kb0 = *(const short8*)&Ks[nt * 16 + lq][quad * 8];
      short8 kb1 = *(const short8*)&Ks[nt * 16 + lq][32 + quad * 8];
#pragma unroll
      for (int mf = 0; mf < 2; ++mf) {
        f32x4 acc = (f32x4){0.f, 0.f, 0.f, 0.f};
        acc = __builtin_amdgcn_mfma_f32_16x16x32_bf16(qa[mf][0], kb0, acc, 0, 0, 0);
        acc = __builtin_amdgcn_mfma_f32_16x16x32_bf16(qa[mf][1], kb1, acc, 0, 0, 0);
        S[mf][nt] = acc;
      }
    }

    // P = exp2(S) -> bf16 (half-up) -> wave-private Pb rows
#pragma unroll
    for (int mf = 0; mf < 2; ++mf)
#pragma unroll
      for (int nt = 0; nt < 4; ++nt)
#pragma unroll
        for (int r = 0; r < 4; ++r) {
          const float p = __builtin_amdgcn_exp2f(S[mf][nt][r]);
          union { float f; unsigned u; } x; x.f = p;
          Pb[wv * 32 + mf * 16 + quad * 4 + r][nt * 16 + lq] =
              (unsigned short)((x.u + 0x8000u) >> 16);
        }
    // no barrier: rows [wv*32, wv*32+32) written & read by wave wv only

    short8 pa[2][2];
#pragma unroll
    for (int mf = 0; mf < 2; ++mf) {
      pa[mf][0] = *(const short8*)&Pb[wv * 32 + mf * 16 + lq][quad * 8];
      pa[mf][1] = *(const short8*)&Pb[wv * 32 + mf * 16 + lq][32 + quad * 8];
    }

#pragma unroll
    for (int dt = 0; dt < 4; ++dt) {
      short8 vb0 = *(const short8*)&Vt[dt * 16 + lq][quad * 8];
      short8 vb1 = *(const short8*)&Vt[dt * 16 + lq][32 + quad * 8];
#pragma unroll
      for (int mf = 0; mf < 2; ++mf) {
        Oacc[mf][dt] =
            __builtin_amdgcn_mfma_f32_16x16x32_bf16(pa[mf][0], vb0, Oacc[mf][dt], 0, 0, 0);
        Oacc[mf][dt] =
            __builtin_amdgcn_mfma_f32_16x16x32_bf16(pa[mf][1], vb1, Oacc[mf][dt], 0, 0, 0);
      }
    }
#pragma unroll
    for (int mf = 0; mf < 2; ++mf) {
      Osum[mf] = __builtin_amdgcn_mfma_f32_16x16x32_bf16(pa[mf][0], ones, Osum[mf], 0, 0, 0);
      Osum[mf] = __builtin_amdgcn_mfma_f32_16x16x32_bf16(pa[mf][1], ones, Osum[mf], 0, 0, 0);
    }
  }

#pragma unroll
  for (int mf = 0; mf < 2; ++mf)
#pragma unroll
    for (int r = 0; r < 4; ++r) {
      const float inv = 1.0f / Osum[mf][r];
      const int qrow = q0 + wv * 32 + mf * 16 + quad * 4 + r;
      unsigned short* base = cc + ((size_t)b * kS + qrow) * kA + h * kDH;
#pragma unroll
      for (int dt = 0; dt < 4; ++dt)
        base[dt * 16 + lq] = f2bf(Oacc[mf][dt][r] * inv);
    }
}

}  // namespace

extern "C" void kernel_launch(void* const* d_in, const int* in_sizes, int n_in,
                              void* d_out, int out_size, void* d_ws, size_t ws_size,
                              hipStream_t stream) {
  const float* x  = (const float*)d_in[0];
  const float* Wq = (const float*)d_in[1];
  const float* bq = (const float*)d_in[2];
  const float* Wk = (const float*)d_in[3];
  const float* bk = (const float*)d_in[4];
  const float* Wv = (const float*)d_in[5];
  const float* bv = (const float*)d_in[6];
  const float* Wo = (const float*)d_in[7];
  const float* bo = (const float*)d_in[8];
  float* out = (float*)d_out;

  const size_t per = (size_t)kBn * kH * kS * kDH;  // 4 Mi elems
  unsigned short* xb  = (unsigned short*)d_ws;
  unsigned short* qb  = xb + per;
  unsigned short* kb  = qb + per;
  unsigned short* vtb = kb + per;
  unsigned short* cc  = vtb + per;
  unsigned short* Wt  = cc + per;          // 3 Mi
  unsigned short* Wot = Wt + 3 * (per / 4);

  cast_x_kernel<<<dim3(per / (256 * 8)), 256, 0, stream>>>(x, xb);
  cast_wqkv_kernel<<<dim3(16, 16, 3), 256, 0, stream>>>(Wq, Wk, Wv, Wt);
  cast_wo_kernel<<<dim3(16, 16), 256, 0, stream>>>(Wo, Wot);

  gemm_bf16_kernel<<<dim3(32, 8, 3), 256, 0, stream>>>(
      xb, Wt, bq, bk, bv, qb, kb, vtb);

  attn_mfma_kernel<<<dim3(kS / QT, kBn * kH), 256, 0, stream>>>(qb, kb, vtb, cc);

  gemm_out_kernel<<<dim3(32, 16), 256, 0, stream>>>(cc, Wot, bo, out);
}